// Round 6
// baseline (476.199 us; speedup 1.0000x reference)
//
#include <hip/hip_runtime.h>
#include <hip/hip_bf16.h>
#include <hip/hip_fp16.h>

typedef _Float16 half8 __attribute__((ext_vector_type(8)));
typedef _Float16 half4 __attribute__((ext_vector_type(4)));
typedef float    floatx4 __attribute__((ext_vector_type(4)));

#define BM  64
#define TPB 4    // tiles per persistent block

// ---------------------------------------------------------------------------
// Kernel 1: W in MFMA-fragment order. Element index:
//   idx = ((((l*4 + wc)*8 + s)*4 + nf)*64 + lane), value block = 8 halves (16 B)
//   content: W^T[n][k] * scale with n = wc*64+nf*16+(lane&15),
//            k = s*32 + (lane>>4)*8 + j
// so a wave's B-fragment load is contiguous: base + lane*16.
// ---------------------------------------------------------------------------
__global__ void make_weights_frag(const float* __restrict__ p0, const float* __restrict__ p1,
                                  const float* __restrict__ p2, const float* __restrict__ p3,
                                  _Float16* __restrict__ wt) {
    int idx  = blockIdx.x * blockDim.x + threadIdx.x;   // 0 .. 24575
    int lane = idx & 63;
    int nf   = (idx >> 6) & 3;
    int s    = (idx >> 8) & 7;
    int wc   = (idx >> 11) & 3;
    int l    = idx >> 13;
    int n  = wc * 64 + nf * 16 + (lane & 15);
    int k0 = s * 32 + (lane >> 4) * 8;
    const float* P[4] = {p0, p1, p2, p3};
    const float* pb = P[l + 1] + n * 20;
    float pbr[20];
    #pragma unroll
    for (int i = 0; i < 20; ++i) pbr[i] = pb[i];
    half8 o;
    #pragma unroll
    for (int j = 0; j < 8; ++j) {
        const float* pa = P[l] + (k0 + j) * 20;
        float d2 = 0.f;
        #pragma unroll
        for (int i = 0; i < 20; ++i) { float df = pa[i] - pbr[i]; d2 += df * df; }
        float d = sqrtf(d2);
        float m = fmodf(d, 0.2f);                            // == np.mod, d >= 0
        o[j] = (_Float16)(10.0f * (0.05f - fabsf(m - 0.1f)) * 0.0625f);
    }
    *reinterpret_cast<half8*>(wt + (size_t)idx * 8) = o;
}

// lgkm-only barrier: does NOT drain vmcnt -> out-stores & W/x prefetch loads
// stay in flight across it. LDS ordering needs lgkmcnt(0) only.
#define LGKM_BAR() do {                                          \
    asm volatile("s_waitcnt lgkmcnt(0)" ::: "memory");           \
    __builtin_amdgcn_s_barrier();                                \
    asm volatile("" ::: "memory");                               \
} while (0)

// ---------------------------------------------------------------------------
// Kernel 2: persistent fused 3-layer forward.
//   512 blocks x 512 threads, TPB=4 tiles of 64 rows each.
//   Two 32 KB XOR-swizzled LDS z-buffers, ping-pong:
//     l0: read X, write X^1.  l1: read X^1, write X.  l2: read X;
//     next tile's x streamed (2-float4 micro-batches, cvt fp16) into X^1
//     inside l2's K-loop. 3 lgkm-only barriers/tile; out-stores never drained.
//   W from global in fragment order (wave-contiguous 1 KB loads), register
//   double-buffered per K-step; next segment's step-0 prefetched pre-barrier.
// ---------------------------------------------------------------------------
__global__ __launch_bounds__(512, 4) void pcn_fused(
    const float* __restrict__ x, const _Float16* __restrict__ wt,
    const float* __restrict__ b1, const float* __restrict__ b2,
    const float* __restrict__ b3, float* __restrict__ out) {

    // z[row][k] in buffer b: byte = b*32768 + row*512 + ((k/8)^(row&7))*16 + (k&7)*2
    __shared__ __align__(16) _Float16 zlds[2][BM * 256];   // 65,536 B

    const int t    = threadIdx.x;
    const int lane = t & 63;
    const int wid  = t >> 6;      // 0..7
    const int wr   = wid >> 2;    // 0..1   (32-row tile)
    const int wc   = wid & 3;     // 0..3   (64-col tile)
    const int l15  = lane & 15;
    const int lg   = lane >> 4;   // 0..3

    char* zbase = reinterpret_cast<char*>(&zlds[0][0]);

    half8   bb[2][4];
    floatx4 acc[2][4];

    const size_t tile0row = (size_t)blockIdx.x * TPB * BM;

    // ---- prologue: stage tile 0 into buffer 0; prefetch layer-0 step-0 W.
    {
        floatx4 xr[8];
        #pragma unroll
        for (int i = 0; i < 8; ++i) {
            int g   = i * 512 + t;        // float4 index in [64][64]
            int row = g >> 6, c4 = g & 63;
            xr[i] = *reinterpret_cast<const floatx4*>(x + (tile0row + row) * 256 + c4 * 4);
        }
        #pragma unroll
        for (int i = 0; i < 8; ++i) {
            int g   = i * 512 + t;
            int row = g >> 6, c4 = g & 63;
            half4 h;
            h[0] = (_Float16)xr[i][0]; h[1] = (_Float16)xr[i][1];
            h[2] = (_Float16)xr[i][2]; h[3] = (_Float16)xr[i][3];
            int chunk = (c4 >> 1) ^ (row & 7);
            *reinterpret_cast<half4*>(zbase + row * 512 + chunk * 16 + (c4 & 1) * 8) = h;
        }
        const _Float16* w0 = wt + ((size_t)wc << 14);
        #pragma unroll
        for (int nf = 0; nf < 4; ++nf)
            bb[0][nf] = *reinterpret_cast<const half8*>(w0 + nf * 512 + lane * 8);
    }
    LGKM_BAR();

    int xb = 0;   // buffer index holding current tile's layer-0 input

    for (int it = 0; it < TPB; ++it) {
        const size_t row0 = tile0row + (size_t)it * BM;
        const bool   pf   = (it + 1 < TPB);

        #pragma unroll
        for (int l = 0; l < 3; ++l) {
            const float* bias = (l == 0) ? b1 : (l == 1) ? b2 : b3;
            const _Float16* wlp = wt + (((size_t)l * 4 + wc) << 14);
            char* rz  = zbase + ((l == 1) ? (xb ^ 1) : xb) * 32768;  // layer input
            char* wzx = zbase + (xb ^ 1) * 32768;                    // next-x dest (l2)

            // bias -> accumulator init
            #pragma unroll
            for (int nf = 0; nf < 4; ++nf) {
                const float bv = bias[wc * 64 + nf * 16 + l15];
                #pragma unroll
                for (int mf = 0; mf < 2; ++mf)
                    acc[mf][nf] = floatx4{bv, bv, bv, bv};
            }

            floatx4 xtmp[2];

            #pragma unroll
            for (int s = 0; s < 8; ++s) {            // K-step of 32
                if (s < 7) {
                    #pragma unroll
                    for (int nf = 0; nf < 4; ++nf)
                        bb[(s + 1) & 1][nf] = *reinterpret_cast<const half8*>(
                            wlp + (s + 1) * 2048 + nf * 512 + lane * 8);
                }
                // next tile's x: micro-batch b = s/2. even s: issue 2 loads;
                // odd s: cvt + ds_write into the free buffer. nothing lives
                // past the K-loop (transient ~16 VGPR).
                if (l == 2 && pf) {
                    const int b = s >> 1;
                    if ((s & 1) == 0) {
                        #pragma unroll
                        for (int j = 0; j < 2; ++j) {
                            int g   = (b * 2 + j) * 512 + t;
                            int row = g >> 6, c4 = g & 63;
                            xtmp[j] = *reinterpret_cast<const floatx4*>(
                                x + (row0 + BM + row) * 256 + c4 * 4);
                        }
                    } else {
                        #pragma unroll
                        for (int j = 0; j < 2; ++j) {
                            int g   = (b * 2 + j) * 512 + t;
                            int row = g >> 6, c4 = g & 63;
                            half4 h;
                            h[0] = (_Float16)xtmp[j][0]; h[1] = (_Float16)xtmp[j][1];
                            h[2] = (_Float16)xtmp[j][2]; h[3] = (_Float16)xtmp[j][3];
                            int chunk = (c4 >> 1) ^ (row & 7);
                            *reinterpret_cast<half4*>(
                                wzx + row * 512 + chunk * 16 + (c4 & 1) * 8) = h;
                        }
                    }
                }

                const int vchunk = (s * 4 + lg) ^ (l15 & 7);
                half8 a[2];
                #pragma unroll
                for (int mf = 0; mf < 2; ++mf)
                    a[mf] = *reinterpret_cast<const half8*>(
                        rz + (wr * 32 + mf * 16 + l15) * 512 + vchunk * 16);
                #pragma unroll
                for (int mf = 0; mf < 2; ++mf)
                    #pragma unroll
                    for (int nf = 0; nf < 4; ++nf)
                        acc[mf][nf] = __builtin_amdgcn_mfma_f32_16x16x32_f16(
                            a[mf], bb[s & 1][nf], acc[mf][nf], 0, 0, 0);
            }

            // prefetch next segment's step-0 W (next layer, or layer 0 again)
            {
                const int lnext = (l < 2) ? (l + 1) : 0;
                const _Float16* wn = wt + (((size_t)lnext * 4 + wc) << 14);
                #pragma unroll
                for (int nf = 0; nf < 4; ++nf)
                    bb[0][nf] = *reinterpret_cast<const half8*>(wn + nf * 512 + lane * 8);
            }

            if (l < 2) {
                // relu + cvt -> the other buffer (write buffer is not being read)
                char* wz = zbase + ((l == 0) ? (xb ^ 1) : xb) * 32768;
                #pragma unroll
                for (int nf = 0; nf < 4; ++nf) {
                    const int n = wc * 64 + nf * 16 + l15;
                    #pragma unroll
                    for (int mf = 0; mf < 2; ++mf) {
                        const int mrow = wr * 32 + mf * 16 + lg * 4;
                        #pragma unroll
                        for (int r = 0; r < 4; ++r) {
                            float v = fmaxf(acc[mf][nf][r], 0.0f);
                            const int row  = mrow + r;
                            const int byte = row * 512 + (((n >> 3) ^ (row & 7)) << 4)
                                           + (n & 7) * 2;
                            *reinterpret_cast<_Float16*>(wz + byte) = (_Float16)v;
                        }
                    }
                }
                LGKM_BAR();
            } else {
                // final layer: f32 out. Stores are never vmcnt-drained by a
                // barrier -> they retire in the background under next tile.
                #pragma unroll
                for (int nf = 0; nf < 4; ++nf) {
                    const int n = wc * 64 + nf * 16 + l15;
                    #pragma unroll
                    for (int mf = 0; mf < 2; ++mf) {
                        const size_t mrow = row0 + wr * 32 + mf * 16 + lg * 4;
                        #pragma unroll
                        for (int r = 0; r < 4; ++r)
                            out[(mrow + r) * 256 + n] = acc[mf][nf][r];
                    }
                }
                LGKM_BAR();   // next-x ds_writes complete; buffer roles swap
            }
        }
        xb ^= 1;
    }
}

extern "C" void kernel_launch(void* const* d_in, const int* in_sizes, int n_in,
                              void* d_out, int out_size, void* d_ws, size_t ws_size,
                              hipStream_t stream) {
    const float* x  = (const float*)d_in[0];
    const float* p0 = (const float*)d_in[1];
    const float* p1 = (const float*)d_in[2];
    const float* p2 = (const float*)d_in[3];
    const float* p3 = (const float*)d_in[4];
    const float* b1 = (const float*)d_in[5];
    const float* b2 = (const float*)d_in[6];
    const float* b3 = (const float*)d_in[7];
    float* out = (float*)d_out;
    _Float16* wt = (_Float16*)d_ws;              // 3*4*8*4*64*8 halves = 384 KB

    const int B = in_sizes[0] / 256;             // 131072

    make_weights_frag<<<96, 256, 0, stream>>>(p0, p1, p2, p3, wt);
    pcn_fused<<<B / (BM * TPB), 512, 0, stream>>>(x, wt, b1, b2, b3, out);
}

// Round 7
// 95.823 us; speedup vs baseline: 4.9696x; 4.9696x over previous
//
#include <hip/hip_runtime.h>
#include <hip/hip_bf16.h>
#include <hip/hip_fp16.h>

typedef _Float16 half8 __attribute__((ext_vector_type(8)));
typedef _Float16 half4 __attribute__((ext_vector_type(4)));
typedef float    floatx4 __attribute__((ext_vector_type(4)));

#define BM 64

// ---------------------------------------------------------------------------
// Kernel 1: W in MFMA-fragment order. Element index:
//   idx = ((((l*4 + wc)*8 + s)*4 + nf)*64 + lane), value block = 8 halves (16 B)
//   content: W^T[n][k] * scale with n = wc*64+nf*16+(lane&15),
//            k = s*32 + (lane>>4)*8 + j
// so a wave's B-fragment load is contiguous: base + lane*16.
// ---------------------------------------------------------------------------
__global__ void make_weights_frag(const float* __restrict__ p0, const float* __restrict__ p1,
                                  const float* __restrict__ p2, const float* __restrict__ p3,
                                  _Float16* __restrict__ wt) {
    int idx  = blockIdx.x * blockDim.x + threadIdx.x;   // 0 .. 24575
    int lane = idx & 63;
    int nf   = (idx >> 6) & 3;
    int s    = (idx >> 8) & 7;
    int wc   = (idx >> 11) & 3;
    int l    = idx >> 13;
    int n  = wc * 64 + nf * 16 + (lane & 15);
    int k0 = s * 32 + (lane >> 4) * 8;
    const float* P[4] = {p0, p1, p2, p3};
    const float* pb = P[l + 1] + n * 20;
    float pbr[20];
    #pragma unroll
    for (int i = 0; i < 20; ++i) pbr[i] = pb[i];
    half8 o;
    #pragma unroll
    for (int j = 0; j < 8; ++j) {
        const float* pa = P[l] + (k0 + j) * 20;
        float d2 = 0.f;
        #pragma unroll
        for (int i = 0; i < 20; ++i) { float df = pa[i] - pbr[i]; d2 += df * df; }
        float d = sqrtf(d2);
        float m = fmodf(d, 0.2f);                            // == np.mod, d >= 0
        o[j] = (_Float16)(10.0f * (0.05f - fabsf(m - 0.1f)) * 0.0625f);
    }
    *reinterpret_cast<half8*>(wt + (size_t)idx * 8) = o;
}

// ---------------------------------------------------------------------------
// Kernel 2: fused 3-layer forward (R4 structure + depth-2 W prefetch + z
// ping-pong).
//   - Block = 64 rows x 256 cols, 512 threads, 8 waves (2x4 grid of 32x64).
//   - z ping-pongs between two 32 KB XOR-swizzled LDS buffers (compile-time
//     pointers): l0 reads buf0 writes buf1; l1 reads buf1 writes buf0;
//     l2 reads buf0. Epilogue writes never alias the buffer being read ->
//     only 3 __syncthreads per block (x-stage, l0-epi, l1-epi).
//   - W from global in fragment order (wave-contiguous 1 KB loads), register
//     ring-buffered TWO K-steps ahead (bb[3][4], static indices via global
//     step g = l*8+s in the fully unrolled 24-step body).
// ---------------------------------------------------------------------------
__global__ __launch_bounds__(512, 4) void pcn_fused(
    const float* __restrict__ x, const _Float16* __restrict__ wt,
    const float* __restrict__ b1, const float* __restrict__ b2,
    const float* __restrict__ b3, float* __restrict__ out) {

    // z[row][k] in buf b: byte = b*32768 + row*512 + ((k/8)^(row&7))*16 + (k&7)*2
    __shared__ __align__(16) _Float16 zlds[2][BM * 256];   // 65,536 B

    const int t    = threadIdx.x;
    const int lane = t & 63;
    const int wid  = t >> 6;      // 0..7
    const int wr   = wid >> 2;    // 0..1   (32-row tile)
    const int wc   = wid & 3;     // 0..3   (64-col tile)
    const int l15  = lane & 15;
    const int lg   = lane >> 4;   // 0..3
    const size_t row0 = (size_t)blockIdx.x * BM;

    char* const zb0 = reinterpret_cast<char*>(&zlds[0][0]);
    char* const zb1 = reinterpret_cast<char*>(&zlds[1][0]);

    half8   bb[3][4];             // ring: step g uses bb[g%3]
    floatx4 acc[2][4];

    // W fragment address for global step g (= l*8 + s), this wave's wc:
    auto wfrag = [&](int g, int nf) -> const half8* {
        const int gl = g >> 3, gs = g & 7;
        return reinterpret_cast<const half8*>(
            wt + (((size_t)gl * 4 + wc) << 14) + gs * 2048 + nf * 512 + lane * 8);
    };

    // ---- stage x: 64x256 f32 -> fp16 swizzled into buf0. 8 float4/thread.
    {
        floatx4 xr[8];
        #pragma unroll
        for (int i = 0; i < 8; ++i) {
            int g   = i * 512 + t;        // float4 index in [64][64]
            int row = g >> 6, c4 = g & 63;
            xr[i] = *reinterpret_cast<const floatx4*>(x + (row0 + row) * 256 + c4 * 4);
        }
        #pragma unroll
        for (int i = 0; i < 8; ++i) {
            int g   = i * 512 + t;
            int row = g >> 6, c4 = g & 63;
            half4 h;
            h[0] = (_Float16)xr[i][0]; h[1] = (_Float16)xr[i][1];
            h[2] = (_Float16)xr[i][2]; h[3] = (_Float16)xr[i][3];
            int chunk = (c4 >> 1) ^ (row & 7);
            *reinterpret_cast<half4*>(zb0 + row * 512 + chunk * 16 + (c4 & 1) * 8) = h;
        }
    }
    // prefetch W steps g=0,1 (layer 0) while x-writes drain
    #pragma unroll
    for (int nf = 0; nf < 4; ++nf) bb[0][nf] = *wfrag(0, nf);
    #pragma unroll
    for (int nf = 0; nf < 4; ++nf) bb[1][nf] = *wfrag(1, nf);
    __syncthreads();

    #pragma unroll
    for (int l = 0; l < 3; ++l) {
        const float* bias = (l == 0) ? b1 : (l == 1) ? b2 : b3;
        char* const rz = (l == 1) ? zb1 : zb0;     // layer input buffer

        // bias -> accumulator init (broadcast along rows)
        #pragma unroll
        for (int nf = 0; nf < 4; ++nf) {
            const float bv = bias[wc * 64 + nf * 16 + l15];
            #pragma unroll
            for (int mf = 0; mf < 2; ++mf)
                acc[mf][nf] = floatx4{bv, bv, bv, bv};
        }

        #pragma unroll
        for (int s = 0; s < 8; ++s) {            // K-step of 32; global step g
            const int g = l * 8 + s;
            // prefetch step g+2 (may cross into next layer; address static)
            if (g + 2 < 24) {
                #pragma unroll
                for (int nf = 0; nf < 4; ++nf)
                    bb[(g + 2) % 3][nf] = *wfrag(g + 2, nf);
            }
            const int vchunk = (s * 4 + lg) ^ (l15 & 7);
            half8 a[2];
            #pragma unroll
            for (int mf = 0; mf < 2; ++mf)
                a[mf] = *reinterpret_cast<const half8*>(
                    rz + (wr * 32 + mf * 16 + l15) * 512 + vchunk * 16);
            #pragma unroll
            for (int mf = 0; mf < 2; ++mf)
                #pragma unroll
                for (int nf = 0; nf < 4; ++nf)
                    acc[mf][nf] = __builtin_amdgcn_mfma_f32_16x16x32_f16(
                        a[mf], bb[g % 3][nf], acc[mf][nf], 0, 0, 0);
        }

        if (l < 2) {
            // relu + cvt -> the OTHER buffer (not being read by anyone)
            char* const wz = (l == 0) ? zb1 : zb0;
            #pragma unroll
            for (int nf = 0; nf < 4; ++nf) {
                const int n = wc * 64 + nf * 16 + l15;
                #pragma unroll
                for (int mf = 0; mf < 2; ++mf) {
                    const int mrow = wr * 32 + mf * 16 + lg * 4;
                    #pragma unroll
                    for (int r = 0; r < 4; ++r) {
                        float v = fmaxf(acc[mf][nf][r], 0.0f);
                        const int row  = mrow + r;
                        const int byte = row * 512 + (((n >> 3) ^ (row & 7)) << 4)
                                       + (n & 7) * 2;
                        *reinterpret_cast<_Float16*>(wz + byte) = (_Float16)v;
                    }
                }
            }
            __syncthreads();
        } else {
            // final layer: f32 out (block exits after; no barrier needed)
            #pragma unroll
            for (int nf = 0; nf < 4; ++nf) {
                const int n = wc * 64 + nf * 16 + l15;
                #pragma unroll
                for (int mf = 0; mf < 2; ++mf) {
                    const size_t mrow = row0 + wr * 32 + mf * 16 + lg * 4;
                    #pragma unroll
                    for (int r = 0; r < 4; ++r)
                        out[(mrow + r) * 256 + n] = acc[mf][nf][r];
                }
            }
        }
    }
}

extern "C" void kernel_launch(void* const* d_in, const int* in_sizes, int n_in,
                              void* d_out, int out_size, void* d_ws, size_t ws_size,
                              hipStream_t stream) {
    const float* x  = (const float*)d_in[0];
    const float* p0 = (const float*)d_in[1];
    const float* p1 = (const float*)d_in[2];
    const float* p2 = (const float*)d_in[3];
    const float* p3 = (const float*)d_in[4];
    const float* b1 = (const float*)d_in[5];
    const float* b2 = (const float*)d_in[6];
    const float* b3 = (const float*)d_in[7];
    float* out = (float*)d_out;
    _Float16* wt = (_Float16*)d_ws;              // 3*4*8*4*64*8 halves = 384 KB

    const int B = in_sizes[0] / 256;             // 131072

    make_weights_frag<<<96, 256, 0, stream>>>(p0, p1, p2, p3, wt);
    pcn_fused<<<B / BM, 512, 0, stream>>>(x, wt, b1, b2, b3, out);
}